// Round 5
// baseline (384.032 us; speedup 1.0000x reference)
//
#include <hip/hip_runtime.h>
#include <math.h>

#define CORNER_L 0.05f

constexpr int THREADS = 256;
constexpr int BLOCKS  = 4096;        // 2 tiles per block
constexpr int TILE_E  = 128;         // elements per tile
// per tile: class 512 f4/array, pose 192 f4/array -> 1408 f4 = 22.5 KB LDS

// Fully scalar, pointer-free pose distance for one element pair.
__device__ __forceinline__ float pose_elem(
    float py, float pp_, float pr, float ptx, float pty, float ptz,
    float ty, float tp_, float tr, float ttx, float tty, float ttz)
{
    float sy1 = __sinf(py),  cy1 = __cosf(py);
    float sp1 = __sinf(pp_), cp1 = __cosf(pp_);
    float sr1 = __sinf(pr),  cr1 = __cosf(pr);
    float sy2 = __sinf(ty),  cy2 = __cosf(ty);
    float sp2 = __sinf(tp_), cp2 = __cosf(tp_);
    float sr2 = __sinf(tr),  cr2 = __cosf(tr);

    float a0 = CORNER_L * (cy1 * cp1 - cy2 * cp2);
    float a1 = CORNER_L * ((cy1 * sp1 * sr1 - sy1 * cr1) - (cy2 * sp2 * sr2 - sy2 * cr2));
    float a2 = CORNER_L * ((cy1 * sp1 * cr1 + sy1 * sr1) - (cy2 * sp2 * cr2 + sy2 * sr2));
    float b0 = CORNER_L * (sy1 * cp1 - sy2 * cp2);
    float b1 = CORNER_L * ((sy1 * sp1 * sr1 + cy1 * cr1) - (sy2 * sp2 * sr2 + cy2 * cr2));
    float b2 = CORNER_L * ((sy1 * sp1 * cr1 - cy1 * sr1) - (sy2 * sp2 * cr2 - cy2 * sr2));
    float c0 = CORNER_L * (sp2 - sp1);
    float c1 = CORNER_L * (cp1 * sr1 - cp2 * sr2);
    float c2 = CORNER_L * (cp1 * cr1 - cp2 * cr2);
    float dtx = ptx - ttx;
    float dty = pty - tty;
    float dtz = ptz - ttz;

    float nsum = 0.0f;
    #pragma unroll
    for (int s = 0; s < 8; ++s) {
        float sx = (s & 4) ? 1.0f : -1.0f;
        float sy = (s & 2) ? 1.0f : -1.0f;
        float sz = (s & 1) ? 1.0f : -1.0f;
        float d0 = sx * a0 + sy * a1 + sz * a2 + dtx;
        float d1 = sx * b0 + sy * b1 + sz * b2 + dty;
        float d2 = sx * c0 + sy * c1 + sz * c2 + dtz;
        nsum += __builtin_amdgcn_sqrtf(d0 * d0 + d1 * d1 + d2 * d2);
    }
    return nsum;
}

// LDS layout (float4 units): [0,512) class_p | [512,1024) class_t
//                            [1024,1216) pose_p | [1216,1408) pose_t
__global__ __launch_bounds__(THREADS) void pose_loss_fused(
    const float4* __restrict__ pp4,
    const float4* __restrict__ pc4,
    const float4* __restrict__ tp4,
    const float4* __restrict__ tc4,
    float* __restrict__ ws,
    float* __restrict__ out,
    float inv_pose, float inv_class)
{
    __shared__ float4 sbuf[1408];
    const int tid  = threadIdx.x;
    const int lane = tid & 63;
    const int wave = tid >> 6;

    float class_acc = 0.0f;
    float pose_acc  = 0.0f;

    for (int it = 0; it < 2; ++it) {
        const size_t tile  = (size_t)blockIdx.x * 2 + it;
        const size_t cbase = tile * 512;   // class float4 base per array
        const size_t pbase = tile * 192;   // pose  float4 base per array

        // ---- burst-stage whole tile into LDS: 22 x 1KB wave-pieces,
        //      zero VGPR destinations, all in flight at once ----
        for (int p = wave; p < 22; p += 4) {
            const float4* src;
            int soff;
            if (p < 8)       { src = pc4 + cbase + (p << 6);        soff = (p << 6); }
            else if (p < 16) { src = tc4 + cbase + ((p - 8) << 6);  soff = 512  + ((p - 8)  << 6); }
            else if (p < 19) { src = pp4 + pbase + ((p - 16) << 6); soff = 1024 + ((p - 16) << 6); }
            else             { src = tp4 + pbase + ((p - 19) << 6); soff = 1216 + ((p - 19) << 6); }
            __builtin_amdgcn_global_load_lds(
                (const __attribute__((address_space(1))) void*)(src + lane),
                (__attribute__((address_space(3))) void*)(&sbuf[soff]),
                16, 0, 0);
        }
        __syncthreads();   // drains vmcnt -> tile resident

        // ---- class MSE: 2 float4 per thread per array, from LDS ----
        {
            float4 a0 = sbuf[tid];        float4 b0 = sbuf[512 + tid];
            float4 a1 = sbuf[256 + tid];  float4 b1 = sbuf[768 + tid];
            float dx, dy, dz, dw;
            dx = a0.x - b0.x; dy = a0.y - b0.y; dz = a0.z - b0.z; dw = a0.w - b0.w;
            class_acc += dx * dx + dy * dy + dz * dz + dw * dw;
            dx = a1.x - b1.x; dy = a1.y - b1.y; dz = a1.z - b1.z; dw = a1.w - b1.w;
            class_acc += dx * dx + dy * dy + dz * dz + dw * dw;
        }

        // ---- pose: 1 element per thread for tid<128 (waves 0-1) ----
        if (tid < TILE_E) {
            const float* sf = (const float*)sbuf;
            const int e6p = 4096 + tid * 6;
            const int e6t = 4864 + tid * 6;
            pose_acc += pose_elem(sf[e6p], sf[e6p + 1], sf[e6p + 2],
                                  sf[e6p + 3], sf[e6p + 4], sf[e6p + 5],
                                  sf[e6t], sf[e6t + 1], sf[e6t + 2],
                                  sf[e6t + 3], sf[e6t + 4], sf[e6t + 5]);
        }
        __syncthreads();   // before next tile overwrites sbuf
    }

    // ---- block reduction ----
    #pragma unroll
    for (int off = 32; off > 0; off >>= 1) {
        pose_acc  += __shfl_down(pose_acc,  off);
        class_acc += __shfl_down(class_acc, off);
    }
    __shared__ float r_pose[4], r_class[4];
    if (lane == 0) { r_pose[wave] = pose_acc; r_class[wave] = class_acc; }
    __syncthreads();

    // ---- device-scope accumulate + last-block finalize ----
    if (tid == 0) {
        float bp = r_pose[0] + r_pose[1] + r_pose[2] + r_pose[3];
        float bc = r_class[0] + r_class[1] + r_class[2] + r_class[3];
        atomicAdd(&ws[0], bp);
        atomicAdd(&ws[1], bc);
        __threadfence();
        unsigned old = atomicAdd((unsigned*)(ws + 2), 1u);
        if (old == (unsigned)(gridDim.x - 1)) {
            // all blocks' atomics are device-visible (fence before counter)
            float lp = atomicAdd(&ws[0], 0.0f) * inv_pose;   // coherent read
            float lc = atomicAdd(&ws[1], 0.0f) * inv_class;
            out[0] = lp + lc;
            out[1] = lp;
            out[2] = lc;
        }
    }
}

extern "C" void kernel_launch(void* const* d_in, const int* in_sizes, int n_in,
                              void* d_out, int out_size, void* d_ws, size_t ws_size,
                              hipStream_t stream) {
    const float4* pred_pose    = (const float4*)d_in[0];
    const float4* pred_class   = (const float4*)d_in[1];
    const float4* target_pose  = (const float4*)d_in[2];
    const float4* target_class = (const float4*)d_in[3];
    float* out = (float*)d_out;
    float* ws  = (float*)d_ws;

    const int B = in_sizes[0] / 6;

    // ws[0]=pose acc, ws[1]=class acc, ws[2]=block counter (poisoned 0xAA each launch)
    hipMemsetAsync(ws, 0, 4 * sizeof(float), stream);

    const float inv_pose  = 1.0f / (8.0f  * (float)B);
    const float inv_class = 1.0f / (16.0f * (float)B);

    pose_loss_fused<<<BLOCKS, THREADS, 0, stream>>>(pred_pose, pred_class,
                                                    target_pose, target_class,
                                                    ws, out, inv_pose, inv_class);
}

// Round 6
// 180.144 us; speedup vs baseline: 2.1318x; 2.1318x over previous
//
#include <hip/hip_runtime.h>
#include <math.h>

#define CORNER_L 0.05f

typedef float f4 __attribute__((ext_vector_type(4)));

constexpr int THREADS = 256;
constexpr int CBLOCKS = 2048;   // class kernel blocks
constexpr int PBLOCKS = 2048;   // pose kernel blocks (524288 threads, 2 elem/thread)

// ---------------- class MSE: pure m13-copy-shape streaming reduce ----------------
__global__ __launch_bounds__(THREADS) void class_mse_kernel(
    const f4* __restrict__ pc4, const f4* __restrict__ tc4,
    float* __restrict__ ws, int n4)
{
    const int tid = threadIdx.x;
    const size_t G = (size_t)CBLOCKS * THREADS;
    float acc = 0.0f;
    for (size_t i = (size_t)blockIdx.x * THREADS + tid; i < (size_t)n4; i += G) {
        f4 p = __builtin_nontemporal_load(pc4 + i);
        f4 t = __builtin_nontemporal_load(tc4 + i);
        f4 d = p - t;
        acc += d.x * d.x + d.y * d.y + d.z * d.z + d.w * d.w;
    }
    #pragma unroll
    for (int off = 32; off > 0; off >>= 1) acc += __shfl_down(acc, off);
    __shared__ float r[4];
    const int lane = tid & 63, wave = tid >> 6;
    if (lane == 0) r[wave] = acc;
    __syncthreads();
    if (tid == 0) ws[blockIdx.x] = r[0] + r[1] + r[2] + r[3];
}

// ---------------- pose: pointer-free trig, 2 elements per thread ----------------
__device__ __forceinline__ float pose_elem(
    float py, float pp_, float pr, float ptx, float pty, float ptz,
    float ty, float tp_, float tr, float ttx, float tty, float ttz)
{
    float sy1 = __sinf(py),  cy1 = __cosf(py);
    float sp1 = __sinf(pp_), cp1 = __cosf(pp_);
    float sr1 = __sinf(pr),  cr1 = __cosf(pr);
    float sy2 = __sinf(ty),  cy2 = __cosf(ty);
    float sp2 = __sinf(tp_), cp2 = __cosf(tp_);
    float sr2 = __sinf(tr),  cr2 = __cosf(tr);

    float a0 = CORNER_L * (cy1 * cp1 - cy2 * cp2);
    float a1 = CORNER_L * ((cy1 * sp1 * sr1 - sy1 * cr1) - (cy2 * sp2 * sr2 - sy2 * cr2));
    float a2 = CORNER_L * ((cy1 * sp1 * cr1 + sy1 * sr1) - (cy2 * sp2 * cr2 + sy2 * sr2));
    float b0 = CORNER_L * (sy1 * cp1 - sy2 * cp2);
    float b1 = CORNER_L * ((sy1 * sp1 * sr1 + cy1 * cr1) - (sy2 * sp2 * sr2 + cy2 * cr2));
    float b2 = CORNER_L * ((sy1 * sp1 * cr1 - cy1 * sr1) - (sy2 * sp2 * cr2 - cy2 * sr2));
    float c0 = CORNER_L * (sp2 - sp1);
    float c1 = CORNER_L * (cp1 * sr1 - cp2 * sr2);
    float c2 = CORNER_L * (cp1 * cr1 - cp2 * cr2);
    float dtx = ptx - ttx;
    float dty = pty - tty;
    float dtz = ptz - ttz;

    float nsum = 0.0f;
    #pragma unroll
    for (int s = 0; s < 8; ++s) {
        float sx = (s & 4) ? 1.0f : -1.0f;
        float sy = (s & 2) ? 1.0f : -1.0f;
        float sz = (s & 1) ? 1.0f : -1.0f;
        float d0 = sx * a0 + sy * a1 + sz * a2 + dtx;
        float d1 = sx * b0 + sy * b1 + sz * b2 + dty;
        float d2 = sx * c0 + sy * c1 + sz * c2 + dtz;
        nsum += __builtin_amdgcn_sqrtf(d0 * d0 + d1 * d1 + d2 * d2);
    }
    return nsum;
}

__global__ __launch_bounds__(THREADS) void pose_kernel(
    const f4* __restrict__ pp4, const f4* __restrict__ tp4,
    float* __restrict__ ws)
{
    const int tid = threadIdx.x;
    const size_t gtid = (size_t)blockIdx.x * THREADS + tid;
    const size_t f = gtid * 3;

    f4 P0 = __builtin_nontemporal_load(pp4 + f);
    f4 P1 = __builtin_nontemporal_load(pp4 + f + 1);
    f4 P2 = __builtin_nontemporal_load(pp4 + f + 2);
    f4 T0 = __builtin_nontemporal_load(tp4 + f);
    f4 T1 = __builtin_nontemporal_load(tp4 + f + 1);
    f4 T2 = __builtin_nontemporal_load(tp4 + f + 2);

    float acc = 0.0f;
    acc += pose_elem(P0.x, P0.y, P0.z, P0.w, P1.x, P1.y,
                     T0.x, T0.y, T0.z, T0.w, T1.x, T1.y);
    acc += pose_elem(P1.z, P1.w, P2.x, P2.y, P2.z, P2.w,
                     T1.z, T1.w, T2.x, T2.y, T2.z, T2.w);

    #pragma unroll
    for (int off = 32; off > 0; off >>= 1) acc += __shfl_down(acc, off);
    __shared__ float r[4];
    const int lane = tid & 63, wave = tid >> 6;
    if (lane == 0) r[wave] = acc;
    __syncthreads();
    if (tid == 0) ws[CBLOCKS + blockIdx.x] = r[0] + r[1] + r[2] + r[3];
}

// ---------------- finalize: reduce 2048 class + 2048 pose partials ----------------
__global__ __launch_bounds__(THREADS) void pose_loss_finalize(
    const float* __restrict__ ws, float* __restrict__ out,
    float inv_pose, float inv_class)
{
    float c = 0.0f, p = 0.0f;
    for (int k = threadIdx.x; k < CBLOCKS; k += THREADS) c += ws[k];
    for (int k = threadIdx.x; k < PBLOCKS; k += THREADS) p += ws[CBLOCKS + k];
    #pragma unroll
    for (int off = 32; off > 0; off >>= 1) {
        p += __shfl_down(p, off);
        c += __shfl_down(c, off);
    }
    __shared__ float r_p[4], r_c[4];
    const int lane = threadIdx.x & 63, wave = threadIdx.x >> 6;
    if (lane == 0) { r_p[wave] = p; r_c[wave] = c; }
    __syncthreads();
    if (threadIdx.x == 0) {
        float lp = (r_p[0] + r_p[1] + r_p[2] + r_p[3]) * inv_pose;
        float lc = (r_c[0] + r_c[1] + r_c[2] + r_c[3]) * inv_class;
        out[0] = lp + lc;
        out[1] = lp;
        out[2] = lc;
    }
}

extern "C" void kernel_launch(void* const* d_in, const int* in_sizes, int n_in,
                              void* d_out, int out_size, void* d_ws, size_t ws_size,
                              hipStream_t stream) {
    const f4* pred_pose    = (const f4*)d_in[0];
    const f4* pred_class   = (const f4*)d_in[1];
    const f4* target_pose  = (const f4*)d_in[2];
    const f4* target_class = (const f4*)d_in[3];
    float* out = (float*)d_out;
    float* ws  = (float*)d_ws;

    const int B  = in_sizes[0] / 6;
    const int n4 = B * 4;   // float4 count per class array

    class_mse_kernel<<<CBLOCKS, THREADS, 0, stream>>>(pred_class, target_class, ws, n4);
    pose_kernel<<<PBLOCKS, THREADS, 0, stream>>>(pred_pose, target_pose, ws);

    const float inv_pose  = 1.0f / (8.0f  * (float)B);
    const float inv_class = 1.0f / (16.0f * (float)B);
    pose_loss_finalize<<<1, THREADS, 0, stream>>>(ws, out, inv_pose, inv_class);
}

// Round 7
// 174.637 us; speedup vs baseline: 2.1990x; 1.0315x over previous
//
#include <hip/hip_runtime.h>
#include <math.h>

#define CORNER_L 0.05f

typedef float f4 __attribute__((ext_vector_type(4)));

constexpr int THREADS = 256;
constexpr int GROUPS  = 1024;
constexpr int CQ = 3, PQ = 2;                    // class:pose block ratio per group
constexpr int CBLOCKS = CQ * GROUPS;             // 3072
constexpr int PBLOCKS = PQ * GROUPS;             // 2048 (524288 threads, 2 elem/thread)
constexpr int TOTAL_BLOCKS = CBLOCKS + PBLOCKS;  // 5120

// Fully scalar, pointer-free pose distance for one element pair.
__device__ __forceinline__ float pose_elem(
    float py, float pp_, float pr, float ptx, float pty, float ptz,
    float ty, float tp_, float tr, float ttx, float tty, float ttz)
{
    float sy1 = __sinf(py),  cy1 = __cosf(py);
    float sp1 = __sinf(pp_), cp1 = __cosf(pp_);
    float sr1 = __sinf(pr),  cr1 = __cosf(pr);
    float sy2 = __sinf(ty),  cy2 = __cosf(ty);
    float sp2 = __sinf(tp_), cp2 = __cosf(tp_);
    float sr2 = __sinf(tr),  cr2 = __cosf(tr);

    float a0 = CORNER_L * (cy1 * cp1 - cy2 * cp2);
    float a1 = CORNER_L * ((cy1 * sp1 * sr1 - sy1 * cr1) - (cy2 * sp2 * sr2 - sy2 * cr2));
    float a2 = CORNER_L * ((cy1 * sp1 * cr1 + sy1 * sr1) - (cy2 * sp2 * cr2 + sy2 * sr2));
    float b0 = CORNER_L * (sy1 * cp1 - sy2 * cp2);
    float b1 = CORNER_L * ((sy1 * sp1 * sr1 + cy1 * cr1) - (sy2 * sp2 * sr2 + cy2 * cr2));
    float b2 = CORNER_L * ((sy1 * sp1 * cr1 - cy1 * sr1) - (sy2 * sp2 * cr2 - cy2 * sr2));
    float c0 = CORNER_L * (sp2 - sp1);
    float c1 = CORNER_L * (cp1 * sr1 - cp2 * sr2);
    float c2 = CORNER_L * (cp1 * cr1 - cp2 * cr2);
    float dtx = ptx - ttx;
    float dty = pty - tty;
    float dtz = ptz - ttz;

    float nsum = 0.0f;
    #pragma unroll
    for (int s = 0; s < 8; ++s) {
        float sx = (s & 4) ? 1.0f : -1.0f;
        float sy = (s & 2) ? 1.0f : -1.0f;
        float sz = (s & 1) ? 1.0f : -1.0f;
        float d0 = sx * a0 + sy * a1 + sz * a2 + dtx;
        float d1 = sx * b0 + sy * b1 + sz * b2 + dty;
        float d2 = sx * c0 + sy * c1 + sz * c2 + dtz;
        nsum += __builtin_amdgcn_sqrtf(d0 * d0 + d1 * d1 + d2 * d2);
    }
    return nsum;
}

// Block-specialized fused kernel: per group of 5 blocks, 3 run the clean
// grid-stride class-MSE stream, 2 run the one-shot pose path. Both types
// co-resident -> pose trig hides under class streaming; BW fully shared.
__global__ __launch_bounds__(THREADS) void pose_loss_fused(
    const f4* __restrict__ pp4, const f4* __restrict__ pc4,
    const f4* __restrict__ tp4, const f4* __restrict__ tc4,
    float* __restrict__ ws, int n4)
{
    const int tid = threadIdx.x;
    const int g   = blockIdx.x;
    const int grp = g / 5;
    const int r   = g - grp * 5;

    float acc = 0.0f;
    int out_idx;

    if (r < CQ) {
        // ---------- class MSE: clean m13-shape grid-stride stream ----------
        const int cb = grp * CQ + r;                 // 0..3071
        const size_t G = (size_t)CBLOCKS * THREADS;
        for (size_t i = (size_t)cb * THREADS + tid; i < (size_t)n4; i += G) {
            f4 p = __builtin_nontemporal_load(pc4 + i);
            f4 t = __builtin_nontemporal_load(tc4 + i);
            f4 d = p - t;
            acc += d.x * d.x + d.y * d.y + d.z * d.z + d.w * d.w;
        }
        out_idx = cb;
    } else {
        // ---------- pose: one-shot 3 f4/array per thread, 2 elements ----------
        const int pb = grp * PQ + (r - CQ);          // 0..2047
        const size_t gtid = (size_t)pb * THREADS + tid;
        const size_t f = gtid * 3;
        f4 P0 = __builtin_nontemporal_load(pp4 + f);
        f4 P1 = __builtin_nontemporal_load(pp4 + f + 1);
        f4 P2 = __builtin_nontemporal_load(pp4 + f + 2);
        f4 T0 = __builtin_nontemporal_load(tp4 + f);
        f4 T1 = __builtin_nontemporal_load(tp4 + f + 1);
        f4 T2 = __builtin_nontemporal_load(tp4 + f + 2);
        acc += pose_elem(P0.x, P0.y, P0.z, P0.w, P1.x, P1.y,
                         T0.x, T0.y, T0.z, T0.w, T1.x, T1.y);
        acc += pose_elem(P1.z, P1.w, P2.x, P2.y, P2.z, P2.w,
                         T1.z, T1.w, T2.x, T2.y, T2.z, T2.w);
        out_idx = CBLOCKS + pb;
    }

    // ---------- common block reduction ----------
    #pragma unroll
    for (int off = 32; off > 0; off >>= 1) acc += __shfl_down(acc, off);
    __shared__ float red[4];
    const int lane = tid & 63, wave = tid >> 6;
    if (lane == 0) red[wave] = acc;
    __syncthreads();
    if (tid == 0) ws[out_idx] = red[0] + red[1] + red[2] + red[3];
}

// finalize: ws[0..CBLOCKS) = class partials, ws[CBLOCKS..TOTAL) = pose partials
__global__ __launch_bounds__(THREADS) void pose_loss_finalize(
    const float* __restrict__ ws, float* __restrict__ out,
    float inv_pose, float inv_class)
{
    float c = 0.0f, p = 0.0f;
    for (int k = threadIdx.x; k < CBLOCKS; k += THREADS) c += ws[k];
    for (int k = threadIdx.x; k < PBLOCKS; k += THREADS) p += ws[CBLOCKS + k];
    #pragma unroll
    for (int off = 32; off > 0; off >>= 1) {
        p += __shfl_down(p, off);
        c += __shfl_down(c, off);
    }
    __shared__ float r_p[4], r_c[4];
    const int lane = threadIdx.x & 63, wave = threadIdx.x >> 6;
    if (lane == 0) { r_p[wave] = p; r_c[wave] = c; }
    __syncthreads();
    if (threadIdx.x == 0) {
        float lp = (r_p[0] + r_p[1] + r_p[2] + r_p[3]) * inv_pose;
        float lc = (r_c[0] + r_c[1] + r_c[2] + r_c[3]) * inv_class;
        out[0] = lp + lc;
        out[1] = lp;
        out[2] = lc;
    }
}

extern "C" void kernel_launch(void* const* d_in, const int* in_sizes, int n_in,
                              void* d_out, int out_size, void* d_ws, size_t ws_size,
                              hipStream_t stream) {
    const f4* pred_pose    = (const f4*)d_in[0];
    const f4* pred_class   = (const f4*)d_in[1];
    const f4* target_pose  = (const f4*)d_in[2];
    const f4* target_class = (const f4*)d_in[3];
    float* out = (float*)d_out;
    float* ws  = (float*)d_ws;

    const int B  = in_sizes[0] / 6;
    const int n4 = B * 4;   // float4 count per class array

    pose_loss_fused<<<TOTAL_BLOCKS, THREADS, 0, stream>>>(
        pred_pose, pred_class, target_pose, target_class, ws, n4);

    const float inv_pose  = 1.0f / (8.0f  * (float)B);
    const float inv_class = 1.0f / (16.0f * (float)B);
    pose_loss_finalize<<<1, THREADS, 0, stream>>>(ws, out, inv_pose, inv_class);
}